// Round 1
// baseline (1351.767 us; speedup 1.0000x reference)
//
#include <hip/hip_runtime.h>
#include <math.h>

#define S_LEN 2048
#define HID   2048
#define NH    32
#define NKV   8
#define HD    64

typedef short short8  __attribute__((ext_vector_type(8)));
typedef float floatx4 __attribute__((ext_vector_type(4)));

static __device__ __forceinline__ ushort f2bf(float f) {
  unsigned u = __float_as_uint(f);
  u += 0x7fffu + ((u >> 16) & 1u);   // RNE; inputs finite
  return (ushort)(u >> 16);
}

// ---------------- fp32 -> bf16 conversion (vectorized x4) ----------------
__global__ void cvt_bf16_kernel(const float* __restrict__ src,
                                ushort* __restrict__ dst, int n4) {
  int i = blockIdx.x * 256 + threadIdx.x;
  if (i >= n4) return;
  float4 v = ((const float4*)src)[i];
  ushort4 o;
  o.x = f2bf(v.x); o.y = f2bf(v.y); o.z = f2bf(v.z); o.w = f2bf(v.w);
  ((ushort4*)dst)[i] = o;
}

// ---------------- C[M][N] = A[M][K] * B[N][K]^T  (bf16 in, fp32 out) ------
// One 16x16 tile per wave via mfma_f32_16x16x32_bf16.
// A-frag: lane holds A[m=lane&15][k0 + (lane>>4)*8 + j], j=0..7 (contiguous 16B)
// B-frag: lane holds B[n=lane&15][k0 + (lane>>4)*8 + j]
// D:      lane,reg -> row = (lane>>4)*4+reg, col = lane&15
__global__ __launch_bounds__(256) void gemm_bt_kernel(
    const ushort* __restrict__ A, const ushort* __restrict__ B,
    float* __restrict__ C, int M, int N, int K) {
  const int wave = threadIdx.x >> 6;
  const int lane = threadIdx.x & 63;
  const int r16  = lane & 15;
  const int quad = lane >> 4;
  const int n0 = (blockIdx.x * 4 + wave) * 16;
  const int m0 = blockIdx.y * 16;
  const ushort* ap = A + (size_t)(m0 + r16) * K + quad * 8;
  const ushort* bp = B + (size_t)(n0 + r16) * K + quad * 8;
  floatx4 acc = {0.f, 0.f, 0.f, 0.f};
#pragma unroll 4
  for (int k = 0; k < K; k += 32) {
    short8 a = *(const short8*)(ap + k);
    short8 b = *(const short8*)(bp + k);
    acc = __builtin_amdgcn_mfma_f32_16x16x32_bf16(a, b, acc, 0, 0, 0);
  }
  const int cn = n0 + r16;
  const int cm = m0 + quad * 4;
#pragma unroll
  for (int r = 0; r < 4; ++r)
    C[(size_t)(cm + r) * N + cn] = acc[r];
}

// ---------------- RoPE + transpose to [nh][S][64] (fp32) ------------------
__global__ void rope_kernel(const float* __restrict__ lin,  // [S][nh*64]
                            float* __restrict__ outp,       // [nh][S][64]
                            const int* __restrict__ pos_ids,
                            int nh, int sh) {
  int idx = blockIdx.x * 256 + threadIdx.x;  // exact: S*nh*32 threads
  int d2 = idx & 31;
  int h  = (idx >> 5) & (nh - 1);
  int s  = idx >> (5 + sh);
  float pos  = (float)pos_ids[s];
  float invf = powf(10000.0f, -(2.0f * (float)d2) * (1.0f / 64.0f));
  float sn, cs;
  sincosf(pos * invf, &sn, &cs);
  float x1 = lin[(size_t)s * (nh * 64) + h * 64 + d2];
  float x2 = lin[(size_t)s * (nh * 64) + h * 64 + d2 + 32];
  outp[((size_t)h * S_LEN + s) * 64 + d2]      = x1 * cs - x2 * sn;
  outp[((size_t)h * S_LEN + s) * 64 + d2 + 32] = x2 * cs + x1 * sn;
}

__global__ void transpose_v_kernel(const float* __restrict__ lin,
                                   float* __restrict__ outp, int nh, int sh) {
  int idx = blockIdx.x * 256 + threadIdx.x;  // exact: S*nh*64 threads
  int d = idx & 63;
  int h = (idx >> 6) & (nh - 1);
  int s = idx >> (6 + sh);
  outp[((size_t)h * S_LEN + s) * 64 + d] = lin[(size_t)s * (nh * 64) + h * 64 + d];
}

// ---------------- causal GQA flash attention (fp32) -----------------------
// grid = (NH, S/32); block = 256 = 4 waves; wave handles 8 queries.
__global__ __launch_bounds__(256) void attn_kernel(
    const float* __restrict__ Q,   // [NH][S][64]  (roped)
    const float* __restrict__ K,   // [NKV][S][64] (roped)
    const float* __restrict__ V,   // [NKV][S][64]
    ushort* __restrict__ O) {      // [S][NH*64] bf16
  __shared__ __align__(16) float Qs[32][68];
  __shared__ __align__(16) float Ks[64][68];
  __shared__ __align__(16) float Vs[64][68];
  __shared__ __align__(16) float Pt[4][64][12];

  const int h    = blockIdx.x;
  const int kh   = h >> 2;            // GROUPS = 4 (repeat_interleave)
  const int q0   = blockIdx.y * 32;
  const int tid  = threadIdx.x;
  const int wave = tid >> 6;
  const int lane = tid & 63;
  const int qw0  = wave * 8;

  {  // stage Q tile (32x64)
    const float4* src = (const float4*)(Q + ((size_t)h * S_LEN + q0) * 64);
    for (int i = tid; i < 512; i += 256) {
      int r = i >> 4, c = i & 15;
      *(float4*)&Qs[r][c * 4] = src[i];
    }
  }

  float m_run[8], l_run[8], alpha[8], Oacc[8];
#pragma unroll
  for (int q = 0; q < 8; ++q) { m_run[q] = -1e30f; l_run[q] = 0.f; Oacc[q] = 0.f; }

  const int ntile = (q0 >> 6) + 1;
  for (int kt = 0; kt < ntile; ++kt) {
    __syncthreads();
    {  // stage K,V tiles (64x64 each)
      const float4* ksrc = (const float4*)(K + ((size_t)kh * S_LEN + (size_t)kt * 64) * 64);
      const float4* vsrc = (const float4*)(V + ((size_t)kh * S_LEN + (size_t)kt * 64) * 64);
      for (int i = tid; i < 1024; i += 256) {
        int r = i >> 4, c = i & 15;
        *(float4*)&Ks[r][c * 4] = ksrc[i];
        *(float4*)&Vs[r][c * 4] = vsrc[i];
      }
    }
    __syncthreads();

    // ---- scores: lane = key j; K row hoisted to registers ----
    float4 kreg[16];
#pragma unroll
    for (int d4 = 0; d4 < 16; ++d4) kreg[d4] = *(const float4*)&Ks[lane][d4 * 4];
    const bool last  = (kt == ntile - 1);
    const int  key_g = kt * 64 + lane;
#pragma unroll
    for (int q = 0; q < 8; ++q) {
      const float4* qrow = (const float4*)&Qs[qw0 + q][0];
      float4 s4 = {0.f, 0.f, 0.f, 0.f};
#pragma unroll
      for (int d4 = 0; d4 < 16; ++d4) {
        float4 qv = qrow[d4];   // LDS broadcast (conflict-free)
        s4.x += qv.x * kreg[d4].x;
        s4.y += qv.y * kreg[d4].y;
        s4.z += qv.z * kreg[d4].z;
        s4.w += qv.w * kreg[d4].w;
      }
      float sc = ((s4.x + s4.y) + (s4.z + s4.w)) * 0.125f;  // 1/sqrt(64)
      if (last && key_g > q0 + qw0 + q) sc = -1e30f;        // causal
      float mx = sc;
#pragma unroll
      for (int off = 32; off > 0; off >>= 1) mx = fmaxf(mx, __shfl_xor(mx, off));
      float mnew = fmaxf(m_run[q], mx);
      float p  = __expf(sc - mnew);
      float ps = p;
#pragma unroll
      for (int off = 32; off > 0; off >>= 1) ps += __shfl_xor(ps, off);
      alpha[q] = __expf(m_run[q] - mnew);   // first iter: exp(-huge) = 0
      l_run[q] = l_run[q] * alpha[q] + ps;
      m_run[q] = mnew;
      Pt[wave][lane][q] = p;
    }
    __syncthreads();

    // ---- PV accumulate: lane = d ----
#pragma unroll
    for (int q = 0; q < 8; ++q) Oacc[q] *= alpha[q];
    for (int j = 0; j < 64; ++j) {
      float v = Vs[j][lane];
      const float4* prow = (const float4*)&Pt[wave][j][0];
      float4 p0 = prow[0], p1 = prow[1];
      Oacc[0] += p0.x * v; Oacc[1] += p0.y * v;
      Oacc[2] += p0.z * v; Oacc[3] += p0.w * v;
      Oacc[4] += p1.x * v; Oacc[5] += p1.y * v;
      Oacc[6] += p1.z * v; Oacc[7] += p1.w * v;
    }
  }

#pragma unroll
  for (int q = 0; q < 8; ++q) {
    float o = Oacc[q] / l_run[q];
    O[(size_t)(q0 + qw0 + q) * (NH * HD) + h * HD + lane] = f2bf(o);
  }
}

// --------------------------------------------------------------------------
extern "C" void kernel_launch(void* const* d_in, const int* in_sizes, int n_in,
                              void* d_out, int out_size, void* d_ws, size_t ws_size,
                              hipStream_t stream) {
  const float* hidden = (const float*)d_in[0];
  // d_in[1] = attention_mask: exactly causal additive -> implemented directly
  const int*   pos    = (const int*)d_in[2];
  const float* Wq     = (const float*)d_in[3];
  const float* Wk     = (const float*)d_in[4];
  const float* Wv     = (const float*)d_in[5];
  const float* Wo     = (const float*)d_in[6];
  float* out = (float*)d_out;

  char* w = (char*)d_ws;
  auto carve = [&](size_t bytes) { char* p = w; w += bytes; return p; };
  ushort* hb   = (ushort*)carve((size_t)S_LEN * HID * 2);      // hidden bf16
  ushort* wqb  = (ushort*)carve((size_t)HID * HID * 2);
  ushort* wkb  = (ushort*)carve((size_t)NKV * HD * HID * 2);
  ushort* wvb  = (ushort*)carve((size_t)NKV * HD * HID * 2);
  ushort* wob  = (ushort*)carve((size_t)HID * HID * 2);
  float*  qlin = (float*)carve((size_t)S_LEN * HID * 4);
  float*  klin = (float*)carve((size_t)S_LEN * NKV * HD * 4);
  float*  vlin = (float*)carve((size_t)S_LEN * NKV * HD * 4);
  float*  qr   = (float*)carve((size_t)NH * S_LEN * HD * 4);
  float*  kr   = (float*)carve((size_t)NKV * S_LEN * HD * 4);
  float*  vr   = (float*)carve((size_t)NKV * S_LEN * HD * 4);
  ushort* ob   = (ushort*)carve((size_t)S_LEN * HID * 2);      // attn out bf16
  // total ~84 MB of d_ws

  // 1) bf16 conversions
  cvt_bf16_kernel<<<(S_LEN * HID / 4) / 256, 256, 0, stream>>>(hidden, hb, S_LEN * HID / 4);
  cvt_bf16_kernel<<<(HID * HID / 4) / 256, 256, 0, stream>>>(Wq, wqb, HID * HID / 4);
  cvt_bf16_kernel<<<(NKV * HD * HID / 4) / 256, 256, 0, stream>>>(Wk, wkb, NKV * HD * HID / 4);
  cvt_bf16_kernel<<<(NKV * HD * HID / 4) / 256, 256, 0, stream>>>(Wv, wvb, NKV * HD * HID / 4);
  cvt_bf16_kernel<<<(HID * HID / 4) / 256, 256, 0, stream>>>(Wo, wob, HID * HID / 4);

  // 2) QKV projections (C = X * W^T)
  dim3 gq(HID / 64, S_LEN / 16);
  gemm_bt_kernel<<<gq, 256, 0, stream>>>(hb, wqb, qlin, S_LEN, HID, HID);
  dim3 gk((NKV * HD) / 64, S_LEN / 16);
  gemm_bt_kernel<<<gk, 256, 0, stream>>>(hb, wkb, klin, S_LEN, NKV * HD, HID);
  gemm_bt_kernel<<<gk, 256, 0, stream>>>(hb, wvb, vlin, S_LEN, NKV * HD, HID);

  // 3) RoPE + head-major transpose (fp32)
  rope_kernel<<<(S_LEN * NH * 32) / 256, 256, 0, stream>>>(qlin, qr, pos, NH, 5);
  rope_kernel<<<(S_LEN * NKV * 32) / 256, 256, 0, stream>>>(klin, kr, pos, NKV, 3);
  transpose_v_kernel<<<(S_LEN * NKV * 64) / 256, 256, 0, stream>>>(vlin, vr, NKV, 3);

  // 4) causal GQA attention -> bf16 [S][NH*HD]
  dim3 ga(NH, S_LEN / 32);
  attn_kernel<<<ga, 256, 0, stream>>>(qr, kr, vr, ob);

  // 5) output projection -> fp32 d_out
  dim3 go(HID / 64, S_LEN / 16);
  gemm_bt_kernel<<<go, 256, 0, stream>>>(ob, wob, out, S_LEN, HID, HID);
}

// Round 3
// 790.403 us; speedup vs baseline: 1.7102x; 1.7102x over previous
//
#include <hip/hip_runtime.h>
#include <math.h>

#define S_LEN 2048
#define HID   2048
#define NH    32
#define NKV   8
#define HD    64

typedef short short8  __attribute__((ext_vector_type(8)));
typedef float floatx4 __attribute__((ext_vector_type(4)));

static __device__ __forceinline__ ushort f2bf(float f) {
  unsigned u = __float_as_uint(f);
  u += 0x7fffu + ((u >> 16) & 1u);   // RNE; inputs finite
  return (ushort)(u >> 16);
}

// ---------------- fp32 -> bf16 conversion (vectorized x4) ----------------
__global__ void cvt_bf16_kernel(const float* __restrict__ src,
                                ushort* __restrict__ dst, int n4) {
  int i = blockIdx.x * 256 + threadIdx.x;
  if (i >= n4) return;
  float4 v = ((const float4*)src)[i];
  ushort4 o;
  o.x = f2bf(v.x); o.y = f2bf(v.y); o.z = f2bf(v.z); o.w = f2bf(v.w);
  ((ushort4*)dst)[i] = o;
}

// ---------------- C[M][N] = A[M][K] * B[N][K]^T  (bf16 in, fp32 out) ------
__global__ __launch_bounds__(256) void gemm_bt_kernel(
    const ushort* __restrict__ A, const ushort* __restrict__ B,
    float* __restrict__ C, int M, int N, int K) {
  const int wave = threadIdx.x >> 6;
  const int lane = threadIdx.x & 63;
  const int r16  = lane & 15;
  const int quad = lane >> 4;
  const int n0 = (blockIdx.x * 4 + wave) * 16;
  const int m0 = blockIdx.y * 16;
  const ushort* ap = A + (size_t)(m0 + r16) * K + quad * 8;
  const ushort* bp = B + (size_t)(n0 + r16) * K + quad * 8;
  floatx4 acc = {0.f, 0.f, 0.f, 0.f};
#pragma unroll 4
  for (int k = 0; k < K; k += 32) {
    short8 a = *(const short8*)(ap + k);
    short8 b = *(const short8*)(bp + k);
    acc = __builtin_amdgcn_mfma_f32_16x16x32_bf16(a, b, acc, 0, 0, 0);
  }
  const int cn = n0 + r16;
  const int cm = m0 + quad * 4;
#pragma unroll
  for (int r = 0; r < 4; ++r)
    C[(size_t)(cm + r) * N + cn] = acc[r];
}

// ---------------- RoPE + transpose to bf16 [nh][S][64] --------------------
__global__ void rope_kernel(const float* __restrict__ lin,  // [S][nh*64]
                            ushort* __restrict__ outp,      // [nh][S][64] bf16
                            const int* __restrict__ pos_ids,
                            int nh, int sh) {
  int idx = blockIdx.x * 256 + threadIdx.x;  // exact: S*nh*32 threads
  int d2 = idx & 31;
  int h  = (idx >> 5) & (nh - 1);
  int s  = idx >> (5 + sh);
  float pos  = (float)pos_ids[s];
  float invf = powf(10000.0f, -(2.0f * (float)d2) * (1.0f / 64.0f));
  float sn, cs;
  sincosf(pos * invf, &sn, &cs);
  float x1 = lin[(size_t)s * (nh * 64) + h * 64 + d2];
  float x2 = lin[(size_t)s * (nh * 64) + h * 64 + d2 + 32];
  outp[((size_t)h * S_LEN + s) * 64 + d2]      = f2bf(x1 * cs - x2 * sn);
  outp[((size_t)h * S_LEN + s) * 64 + d2 + 32] = f2bf(x2 * cs + x1 * sn);
}

// ---------------- V: [S][NKV*64] fp32 -> bf16 Vt [NKV][64][S] -------------
__global__ void transpose_v_kernel(const float* __restrict__ lin,
                                   ushort* __restrict__ vt) {
  int idx = blockIdx.x * 256 + threadIdx.x;  // NKV*HD*(S/4) threads
  int s4 = idx & (S_LEN / 4 - 1);
  int d  = (idx >> 9) & 63;
  int h  = idx >> 15;
  const float* src = lin + (size_t)(s4 * 4) * (NKV * HD) + h * 64 + d;
  ushort4 o;
  o.x = f2bf(src[0 * NKV * HD]);
  o.y = f2bf(src[1 * NKV * HD]);
  o.z = f2bf(src[2 * NKV * HD]);
  o.w = f2bf(src[3 * NKV * HD]);
  ((ushort4*)vt)[idx] = o;  // vt[h][d][s4*4 .. +3]
}

// ---------------- causal GQA flash attention (MFMA bf16) ------------------
// grid = (NH, S/64); block = 256 = 4 waves; wave handles 16 q-rows.
#define LOG2E_SC 0.180336880f   // (1/sqrt(64)) * log2(e)

__global__ __launch_bounds__(256) void attn_kernel(
    const ushort* __restrict__ Q,   // [NH][S][64]  bf16 roped
    const ushort* __restrict__ K,   // [NKV][S][64] bf16 roped
    const ushort* __restrict__ Vt,  // [NKV][64][S] bf16
    ushort* __restrict__ O) {       // [S][NH*64]   bf16
  __shared__ __align__(16) ushort Ks[64][72];      // K tile  [k][d]
  __shared__ __align__(16) ushort Vs[64][72];      // Vt tile [d][k]
  __shared__ __align__(16) ushort Ps[4][16][72];   // per-wave P [q][k]

  const int h    = blockIdx.x;
  const int kh   = h >> 2;                         // GROUPS = 4
  const int y    = blockIdx.y;
  const int qt   = (y & 1) ? (31 - (y >> 1)) : (y >> 1);  // load balance
  const int tid  = threadIdx.x;
  const int wave = tid >> 6;
  const int lane = tid & 63;
  const int r16  = lane & 15;
  const int quad = lane >> 4;

  // Q fragments (held in registers for whole block)
  const ushort* qp = Q + ((size_t)h * S_LEN + qt * 64 + wave * 16 + r16) * 64 + quad * 8;
  const short8 qf0 = *(const short8*)(qp);
  const short8 qf1 = *(const short8*)(qp + 32);

  float m_run[4], l_run[4];
  floatx4 oacc[4];
#pragma unroll
  for (int r = 0; r < 4; ++r) { m_run[r] = -1e30f; l_run[r] = 0.f; }
#pragma unroll
  for (int n = 0; n < 4; ++n) oacc[n] = floatx4{0.f, 0.f, 0.f, 0.f};

  for (int kt = 0; kt <= qt; ++kt) {
    __syncthreads();
    {  // stage K tile + Vt tile (64x64 bf16 each), coalesced b128
      const ushort* ksrc = K  + ((size_t)kh * S_LEN + kt * 64) * 64;
      const ushort* vsrc = Vt + ((size_t)kh * 64) * S_LEN + kt * 64;
#pragma unroll
      for (int i = tid; i < 512; i += 256) {
        int r = i >> 3, c = (i & 7) * 8;
        *(short8*)&Ks[r][c] = *(const short8*)(ksrc + (size_t)r * 64 + c);
        *(short8*)&Vs[r][c] = *(const short8*)(vsrc + (size_t)r * S_LEN + c);
      }
    }
    __syncthreads();

    // ---- scores: 4 col-tiles of 16 keys, D[m=q][n=key] ----
    floatx4 sacc[4];
#pragma unroll
    for (int t = 0; t < 4; ++t) {
      short8 kf0 = *(const short8*)&Ks[t * 16 + r16][quad * 8];
      short8 kf1 = *(const short8*)&Ks[t * 16 + r16][32 + quad * 8];
      floatx4 z = {0.f, 0.f, 0.f, 0.f};
      z = __builtin_amdgcn_mfma_f32_16x16x32_bf16(qf0, kf0, z, 0, 0, 0);
      sacc[t] = __builtin_amdgcn_mfma_f32_16x16x32_bf16(qf1, kf1, z, 0, 0, 0);
    }

    // scale into base-2 domain + causal mask (diagonal tile only)
    const bool diag = (kt == qt);
#pragma unroll
    for (int t = 0; t < 4; ++t)
#pragma unroll
      for (int r = 0; r < 4; ++r) {
        float sc = sacc[t][r] * LOG2E_SC;
        if (diag && (t * 16 + r16) > (wave * 16 + quad * 4 + r)) sc = -1e30f;
        sacc[t][r] = sc;
      }

    // ---- online softmax per q-row (row = quad*4+r, replicated over 16 lanes)
#pragma unroll
    for (int r = 0; r < 4; ++r) {
      float mx = fmaxf(fmaxf(sacc[0][r], sacc[1][r]), fmaxf(sacc[2][r], sacc[3][r]));
#pragma unroll
      for (int off = 8; off > 0; off >>= 1) mx = fmaxf(mx, __shfl_xor(mx, off));
      float mnew  = fmaxf(m_run[r], mx);
      float alpha = __builtin_amdgcn_exp2f(m_run[r] - mnew);
      m_run[r] = mnew;
      float ps = 0.f;
#pragma unroll
      for (int t = 0; t < 4; ++t) {
        float p = __builtin_amdgcn_exp2f(sacc[t][r] - mnew);
        ps += p;
        Ps[wave][quad * 4 + r][t * 16 + r16] = f2bf(p);
      }
#pragma unroll
      for (int off = 8; off > 0; off >>= 1) ps += __shfl_xor(ps, off);
      l_run[r] = l_run[r] * alpha + ps;
#pragma unroll
      for (int n = 0; n < 4; ++n) oacc[n][r] *= alpha;
    }

    // ---- PV: A = P (own wave's LDS region, no barrier needed), B = Vt ----
    short8 pf0 = *(const short8*)&Ps[wave][r16][quad * 8];
    short8 pf1 = *(const short8*)&Ps[wave][r16][32 + quad * 8];
#pragma unroll
    for (int n = 0; n < 4; ++n) {
      short8 vf0 = *(const short8*)&Vs[n * 16 + r16][quad * 8];
      short8 vf1 = *(const short8*)&Vs[n * 16 + r16][32 + quad * 8];
      oacc[n] = __builtin_amdgcn_mfma_f32_16x16x32_bf16(pf0, vf0, oacc[n], 0, 0, 0);
      oacc[n] = __builtin_amdgcn_mfma_f32_16x16x32_bf16(pf1, vf1, oacc[n], 0, 0, 0);
    }
  }

  // epilogue: O[q][h*64+d] = oacc / l
#pragma unroll
  for (int r = 0; r < 4; ++r) {
    float inv_l = 1.f / l_run[r];
    int row = qt * 64 + wave * 16 + quad * 4 + r;
#pragma unroll
    for (int n = 0; n < 4; ++n)
      O[(size_t)row * (NH * HD) + h * 64 + n * 16 + r16] = f2bf(oacc[n][r] * inv_l);
  }
}

// --------------------------------------------------------------------------
extern "C" void kernel_launch(void* const* d_in, const int* in_sizes, int n_in,
                              void* d_out, int out_size, void* d_ws, size_t ws_size,
                              hipStream_t stream) {
  const float* hidden = (const float*)d_in[0];
  const int*   pos    = (const int*)d_in[2];
  const float* Wq     = (const float*)d_in[3];
  const float* Wk     = (const float*)d_in[4];
  const float* Wv     = (const float*)d_in[5];
  const float* Wo     = (const float*)d_in[6];
  float* out = (float*)d_out;

  char* w = (char*)d_ws;
  auto carve = [&](size_t bytes) { char* p = w; w += bytes; return p; };
  ushort* hb   = (ushort*)carve((size_t)S_LEN * HID * 2);
  ushort* wqb  = (ushort*)carve((size_t)HID * HID * 2);
  ushort* wkb  = (ushort*)carve((size_t)NKV * HD * HID * 2);
  ushort* wvb  = (ushort*)carve((size_t)NKV * HD * HID * 2);
  ushort* wob  = (ushort*)carve((size_t)HID * HID * 2);
  float*  qlin = (float*)carve((size_t)S_LEN * HID * 4);
  float*  klin = (float*)carve((size_t)S_LEN * NKV * HD * 4);
  float*  vlin = (float*)carve((size_t)S_LEN * NKV * HD * 4);
  ushort* qr   = (ushort*)carve((size_t)NH * S_LEN * HD * 2);   // bf16
  ushort* kr   = (ushort*)carve((size_t)NKV * S_LEN * HD * 2);  // bf16
  ushort* vtb  = (ushort*)carve((size_t)NKV * HD * S_LEN * 2);  // bf16 [h][d][s]
  ushort* ob   = (ushort*)carve((size_t)S_LEN * HID * 2);

  // 1) bf16 conversions
  cvt_bf16_kernel<<<(S_LEN * HID / 4) / 256, 256, 0, stream>>>(hidden, hb, S_LEN * HID / 4);
  cvt_bf16_kernel<<<(HID * HID / 4) / 256, 256, 0, stream>>>(Wq, wqb, HID * HID / 4);
  cvt_bf16_kernel<<<(NKV * HD * HID / 4) / 256, 256, 0, stream>>>(Wk, wkb, NKV * HD * HID / 4);
  cvt_bf16_kernel<<<(NKV * HD * HID / 4) / 256, 256, 0, stream>>>(Wv, wvb, NKV * HD * HID / 4);
  cvt_bf16_kernel<<<(HID * HID / 4) / 256, 256, 0, stream>>>(Wo, wob, HID * HID / 4);

  // 2) QKV projections (C = X * W^T)
  dim3 gq(HID / 64, S_LEN / 16);
  gemm_bt_kernel<<<gq, 256, 0, stream>>>(hb, wqb, qlin, S_LEN, HID, HID);
  dim3 gk((NKV * HD) / 64, S_LEN / 16);
  gemm_bt_kernel<<<gk, 256, 0, stream>>>(hb, wkb, klin, S_LEN, NKV * HD, HID);
  gemm_bt_kernel<<<gk, 256, 0, stream>>>(hb, wvb, vlin, S_LEN, NKV * HD, HID);

  // 3) RoPE (-> bf16 head-major) + V transpose (-> bf16 [h][d][s])
  rope_kernel<<<(S_LEN * NH * 32) / 256, 256, 0, stream>>>(qlin, qr, pos, NH, 5);
  rope_kernel<<<(S_LEN * NKV * 32) / 256, 256, 0, stream>>>(klin, kr, pos, NKV, 3);
  transpose_v_kernel<<<(NKV * HD * S_LEN / 4) / 256, 256, 0, stream>>>(vlin, vtb);

  // 4) causal GQA attention (MFMA) -> bf16 [S][NH*HD]
  dim3 ga(NH, S_LEN / 64);
  attn_kernel<<<ga, 256, 0, stream>>>(qr, kr, vtb, ob);

  // 5) output projection -> fp32 d_out
  dim3 go(HID / 64, S_LEN / 16);
  gemm_bt_kernel<<<go, 256, 0, stream>>>(ob, wob, out, S_LEN, HID, HID);
}

// Round 4
// 330.256 us; speedup vs baseline: 4.0931x; 2.3933x over previous
//
#include <hip/hip_runtime.h>
#include <math.h>

#define S_LEN 2048
#define HID   2048
#define NH    32
#define NKV   8
#define HD    64
#define BK    32

typedef short short8  __attribute__((ext_vector_type(8)));
typedef float floatx4 __attribute__((ext_vector_type(4)));

static __device__ __forceinline__ ushort f2bf(float f) {
  unsigned u = __float_as_uint(f);
  u += 0x7fffu + ((u >> 16) & 1u);   // RNE; inputs finite
  return (ushort)(u >> 16);
}

// async global->LDS, 16B per lane; LDS dest = wave-uniform base + lane*16
static __device__ __forceinline__ void gl2lds16(const ushort* g, ushort* l) {
  __builtin_amdgcn_global_load_lds(
      (const __attribute__((address_space(1))) unsigned int*)g,
      (__attribute__((address_space(3))) unsigned int*)l, 16, 0, 0);
}

// ---------------- fp32 -> bf16 conversion (vectorized x4) ----------------
__global__ void cvt_bf16_kernel(const float* __restrict__ src,
                                ushort* __restrict__ dst, int n4) {
  int i = blockIdx.x * 256 + threadIdx.x;
  if (i >= n4) return;
  float4 v = ((const float4*)src)[i];
  ushort4 o;
  o.x = f2bf(v.x); o.y = f2bf(v.y); o.z = f2bf(v.z); o.w = f2bf(v.w);
  ((ushort4*)dst)[i] = o;
}

// ------- C[M][N] = A[M][K] * B[N][K]^T, 128x128 tile, global_load_lds -----
// block = 256 (4 waves); wave owns a 64x64 quadrant (4x4 16x16 MFMA tiles).
__global__ __launch_bounds__(256) void gemm128_bt_kernel(
    const ushort* __restrict__ A, const ushort* __restrict__ B,
    float* __restrict__ C, int M, int N, int K) {
  __shared__ __align__(16) ushort As[128 * BK];  // row-major [128][32], no pad
  __shared__ __align__(16) ushort Bs[128 * BK];

  const int tid  = threadIdx.x;
  const int wave = tid >> 6;
  const int lane = tid & 63;
  const int r16  = lane & 15;
  const int quad = lane >> 4;

  const int m_base = blockIdx.y * 128;
  const int n_base = blockIdx.x * 128;
  const int wm = (wave & 1) * 64;
  const int wn = (wave >> 1) * 64;

  // staging: wave w fills rows w*32..w*32+31 of As and Bs (2 calls each)
  const int srow = wave * 32 + (lane >> 2);
  const int scol = (lane & 3) * 8;
  const ushort* ag0 = A + (size_t)(m_base + srow) * K + scol;
  const ushort* ag1 = ag0 + (size_t)16 * K;
  const ushort* bg0 = B + (size_t)(n_base + srow) * K + scol;
  const ushort* bg1 = bg0 + (size_t)16 * K;
  ushort* as0 = As + (wave * 32) * BK;
  ushort* as1 = As + (wave * 32 + 16) * BK;
  ushort* bs0 = Bs + (wave * 32) * BK;
  ushort* bs1 = Bs + (wave * 32 + 16) * BK;

  floatx4 acc[4][4];
#pragma unroll
  for (int i = 0; i < 4; ++i)
#pragma unroll
    for (int j = 0; j < 4; ++j) acc[i][j] = floatx4{0.f, 0.f, 0.f, 0.f};

  for (int kk = 0; kk < K; kk += BK) {
    __syncthreads();
    gl2lds16(ag0 + kk, as0);
    gl2lds16(ag1 + kk, as1);
    gl2lds16(bg0 + kk, bs0);
    gl2lds16(bg1 + kk, bs1);
    __syncthreads();

    short8 af[4], bf[4];
#pragma unroll
    for (int i = 0; i < 4; ++i)
      af[i] = *(const short8*)&As[(wm + i * 16 + r16) * BK + quad * 8];
#pragma unroll
    for (int j = 0; j < 4; ++j)
      bf[j] = *(const short8*)&Bs[(wn + j * 16 + r16) * BK + quad * 8];
#pragma unroll
    for (int i = 0; i < 4; ++i)
#pragma unroll
      for (int j = 0; j < 4; ++j)
        acc[i][j] = __builtin_amdgcn_mfma_f32_16x16x32_bf16(af[i], bf[j], acc[i][j], 0, 0, 0);
  }

#pragma unroll
  for (int i = 0; i < 4; ++i)
#pragma unroll
    for (int j = 0; j < 4; ++j) {
      const int cm = m_base + wm + i * 16 + quad * 4;
      const int cn = n_base + wn + j * 16 + r16;
#pragma unroll
      for (int r = 0; r < 4; ++r)
        C[(size_t)(cm + r) * N + cn] = acc[i][j][r];
    }
}

// ---------------- RoPE + transpose to bf16 [nh][S][64] --------------------
__global__ void rope_kernel(const float* __restrict__ lin,  // [S][ld] (+col off)
                            ushort* __restrict__ outp,      // [nh][S][64] bf16
                            const int* __restrict__ pos_ids,
                            int nh, int sh, int ld) {
  int idx = blockIdx.x * 256 + threadIdx.x;  // exact: S*nh*32 threads
  int d2 = idx & 31;
  int h  = (idx >> 5) & (nh - 1);
  int s  = idx >> (5 + sh);
  float pos  = (float)pos_ids[s];
  float invf = powf(10000.0f, -(2.0f * (float)d2) * (1.0f / 64.0f));
  float sn, cs;
  sincosf(pos * invf, &sn, &cs);
  float x1 = lin[(size_t)s * ld + h * 64 + d2];
  float x2 = lin[(size_t)s * ld + h * 64 + d2 + 32];
  outp[((size_t)h * S_LEN + s) * 64 + d2]      = f2bf(x1 * cs - x2 * sn);
  outp[((size_t)h * S_LEN + s) * 64 + d2 + 32] = f2bf(x2 * cs + x1 * sn);
}

// ---------------- V cols of fused out -> bf16 Vt [NKV][64][S] -------------
__global__ void transpose_v_kernel(const float* __restrict__ lin,  // +col off
                                   ushort* __restrict__ vt, int ld) {
  int idx = blockIdx.x * 256 + threadIdx.x;  // NKV*HD*(S/4) threads
  int s4 = idx & (S_LEN / 4 - 1);
  int d  = (idx >> 9) & 63;
  int h  = idx >> 15;
  const float* src = lin + (size_t)(s4 * 4) * ld + h * 64 + d;
  ushort4 o;
  o.x = f2bf(src[0 * ld]);
  o.y = f2bf(src[1 * ld]);
  o.z = f2bf(src[2 * ld]);
  o.w = f2bf(src[3 * ld]);
  ((ushort4*)vt)[idx] = o;  // vt[h][d][s4*4 .. +3]
}

// ---------------- causal GQA flash attention (MFMA bf16) ------------------
#define LOG2E_SC 0.180336880f   // (1/sqrt(64)) * log2(e)

__global__ __launch_bounds__(256) void attn_kernel(
    const ushort* __restrict__ Q,   // [NH][S][64]  bf16 roped
    const ushort* __restrict__ K,   // [NKV][S][64] bf16 roped
    const ushort* __restrict__ Vt,  // [NKV][64][S] bf16
    ushort* __restrict__ O) {       // [S][NH*64]   bf16
  __shared__ __align__(16) ushort Ks[64][72];      // K tile  [k][d]
  __shared__ __align__(16) ushort Vs[64][72];      // Vt tile [d][k]
  __shared__ __align__(16) ushort Ps[4][16][72];   // per-wave P [q][k]

  const int h    = blockIdx.x;
  const int kh   = h >> 2;                         // GROUPS = 4
  const int y    = blockIdx.y;
  const int qt   = (y & 1) ? (31 - (y >> 1)) : (y >> 1);  // load balance
  const int tid  = threadIdx.x;
  const int wave = tid >> 6;
  const int lane = tid & 63;
  const int r16  = lane & 15;
  const int quad = lane >> 4;

  const ushort* qp = Q + ((size_t)h * S_LEN + qt * 64 + wave * 16 + r16) * 64 + quad * 8;
  const short8 qf0 = *(const short8*)(qp);
  const short8 qf1 = *(const short8*)(qp + 32);

  float m_run[4], l_run[4];
  floatx4 oacc[4];
#pragma unroll
  for (int r = 0; r < 4; ++r) { m_run[r] = -1e30f; l_run[r] = 0.f; }
#pragma unroll
  for (int n = 0; n < 4; ++n) oacc[n] = floatx4{0.f, 0.f, 0.f, 0.f};

  for (int kt = 0; kt <= qt; ++kt) {
    __syncthreads();
    {
      const ushort* ksrc = K  + ((size_t)kh * S_LEN + kt * 64) * 64;
      const ushort* vsrc = Vt + ((size_t)kh * 64) * S_LEN + kt * 64;
#pragma unroll
      for (int i = tid; i < 512; i += 256) {
        int r = i >> 3, c = (i & 7) * 8;
        *(short8*)&Ks[r][c] = *(const short8*)(ksrc + (size_t)r * 64 + c);
        *(short8*)&Vs[r][c] = *(const short8*)(vsrc + (size_t)r * S_LEN + c);
      }
    }
    __syncthreads();

    floatx4 sacc[4];
#pragma unroll
    for (int t = 0; t < 4; ++t) {
      short8 kf0 = *(const short8*)&Ks[t * 16 + r16][quad * 8];
      short8 kf1 = *(const short8*)&Ks[t * 16 + r16][32 + quad * 8];
      floatx4 z = {0.f, 0.f, 0.f, 0.f};
      z = __builtin_amdgcn_mfma_f32_16x16x32_bf16(qf0, kf0, z, 0, 0, 0);
      sacc[t] = __builtin_amdgcn_mfma_f32_16x16x32_bf16(qf1, kf1, z, 0, 0, 0);
    }

    const bool diag = (kt == qt);
#pragma unroll
    for (int t = 0; t < 4; ++t)
#pragma unroll
      for (int r = 0; r < 4; ++r) {
        float sc = sacc[t][r] * LOG2E_SC;
        if (diag && (t * 16 + r16) > (wave * 16 + quad * 4 + r)) sc = -1e30f;
        sacc[t][r] = sc;
      }

#pragma unroll
    for (int r = 0; r < 4; ++r) {
      float mx = fmaxf(fmaxf(sacc[0][r], sacc[1][r]), fmaxf(sacc[2][r], sacc[3][r]));
#pragma unroll
      for (int off = 8; off > 0; off >>= 1) mx = fmaxf(mx, __shfl_xor(mx, off));
      float mnew  = fmaxf(m_run[r], mx);
      float alpha = __builtin_amdgcn_exp2f(m_run[r] - mnew);
      m_run[r] = mnew;
      float ps = 0.f;
#pragma unroll
      for (int t = 0; t < 4; ++t) {
        float p = __builtin_amdgcn_exp2f(sacc[t][r] - mnew);
        ps += p;
        Ps[wave][quad * 4 + r][t * 16 + r16] = f2bf(p);
      }
#pragma unroll
      for (int off = 8; off > 0; off >>= 1) ps += __shfl_xor(ps, off);
      l_run[r] = l_run[r] * alpha + ps;
#pragma unroll
      for (int n = 0; n < 4; ++n) oacc[n][r] *= alpha;
    }

    short8 pf0 = *(const short8*)&Ps[wave][r16][quad * 8];
    short8 pf1 = *(const short8*)&Ps[wave][r16][32 + quad * 8];
#pragma unroll
    for (int n = 0; n < 4; ++n) {
      short8 vf0 = *(const short8*)&Vs[n * 16 + r16][quad * 8];
      short8 vf1 = *(const short8*)&Vs[n * 16 + r16][32 + quad * 8];
      oacc[n] = __builtin_amdgcn_mfma_f32_16x16x32_bf16(pf0, vf0, oacc[n], 0, 0, 0);
      oacc[n] = __builtin_amdgcn_mfma_f32_16x16x32_bf16(pf1, vf1, oacc[n], 0, 0, 0);
    }
  }

#pragma unroll
  for (int r = 0; r < 4; ++r) {
    float inv_l = 1.f / l_run[r];
    int row = qt * 64 + wave * 16 + quad * 4 + r;
#pragma unroll
    for (int n = 0; n < 4; ++n)
      O[(size_t)row * (NH * HD) + h * 64 + n * 16 + r16] = f2bf(oacc[n][r] * inv_l);
  }
}

// --------------------------------------------------------------------------
extern "C" void kernel_launch(void* const* d_in, const int* in_sizes, int n_in,
                              void* d_out, int out_size, void* d_ws, size_t ws_size,
                              hipStream_t stream) {
  const float* hidden = (const float*)d_in[0];
  const int*   pos    = (const int*)d_in[2];
  const float* Wq     = (const float*)d_in[3];
  const float* Wk     = (const float*)d_in[4];
  const float* Wv     = (const float*)d_in[5];
  const float* Wo     = (const float*)d_in[6];
  float* out = (float*)d_out;

  const int NQKV = HID + 2 * NKV * HD;  // 3072 fused output cols

  char* w = (char*)d_ws;
  auto carve = [&](size_t bytes) { char* p = w; w += bytes; return p; };
  ushort* hb    = (ushort*)carve((size_t)S_LEN * HID * 2);
  ushort* wqkvb = (ushort*)carve((size_t)NQKV * HID * 2);    // concat(Wq,Wk,Wv)
  ushort* wob   = (ushort*)carve((size_t)HID * HID * 2);
  float*  qkvl  = (float*)carve((size_t)S_LEN * NQKV * 4);   // fused [S][3072]
  ushort* qr    = (ushort*)carve((size_t)NH * S_LEN * HD * 2);
  ushort* kr    = (ushort*)carve((size_t)NKV * S_LEN * HD * 2);
  ushort* vtb   = (ushort*)carve((size_t)NKV * HD * S_LEN * 2);
  ushort* ob    = (ushort*)carve((size_t)S_LEN * HID * 2);

  // 1) bf16 conversions (weights concatenated row-wise: Wq | Wk | Wv)
  cvt_bf16_kernel<<<(S_LEN * HID / 4) / 256, 256, 0, stream>>>(hidden, hb, S_LEN * HID / 4);
  cvt_bf16_kernel<<<(HID * HID / 4) / 256, 256, 0, stream>>>(Wq, wqkvb, HID * HID / 4);
  cvt_bf16_kernel<<<(NKV * HD * HID / 4) / 256, 256, 0, stream>>>(
      Wk, wqkvb + (size_t)HID * HID, NKV * HD * HID / 4);
  cvt_bf16_kernel<<<(NKV * HD * HID / 4) / 256, 256, 0, stream>>>(
      Wv, wqkvb + (size_t)(HID + NKV * HD) * HID, NKV * HD * HID / 4);
  cvt_bf16_kernel<<<(HID * HID / 4) / 256, 256, 0, stream>>>(Wo, wob, HID * HID / 4);

  // 2) fused QKV projection: [2048][2048] x [3072][2048]^T -> [2048][3072]
  dim3 gqkv(NQKV / 128, S_LEN / 128);
  gemm128_bt_kernel<<<gqkv, 256, 0, stream>>>(hb, wqkvb, qkvl, S_LEN, NQKV, HID);

  // 3) RoPE (-> bf16 head-major) + V transpose (-> bf16 [h][d][s])
  rope_kernel<<<(S_LEN * NH * 32) / 256, 256, 0, stream>>>(qkvl, qr, pos, NH, 5, NQKV);
  rope_kernel<<<(S_LEN * NKV * 32) / 256, 256, 0, stream>>>(qkvl + HID, kr, pos, NKV, 3, NQKV);
  transpose_v_kernel<<<(NKV * HD * S_LEN / 4) / 256, 256, 0, stream>>>(
      qkvl + HID + NKV * HD, vtb, NQKV);

  // 4) causal GQA attention (MFMA) -> bf16 [S][NH*HD]
  dim3 ga(NH, S_LEN / 64);
  attn_kernel<<<ga, 256, 0, stream>>>(qr, kr, vtb, ob);

  // 5) output projection -> fp32 d_out
  dim3 go(HID / 128, S_LEN / 128);
  gemm128_bt_kernel<<<go, 256, 0, stream>>>(ob, wob, out, S_LEN, HID, HID);
}

// Round 7
// 302.352 us; speedup vs baseline: 4.4708x; 1.0923x over previous
//
#include <hip/hip_runtime.h>
#include <math.h>

#define S_LEN 2048
#define HID   2048
#define NH    32
#define NKV   8
#define HD    64
#define BK    32

typedef short short4x __attribute__((ext_vector_type(4)));
typedef short short8  __attribute__((ext_vector_type(8)));
typedef float floatx4 __attribute__((ext_vector_type(4)));

static __device__ __forceinline__ ushort f2bf(float f) {
  unsigned u = __float_as_uint(f);
  u += 0x7fffu + ((u >> 16) & 1u);   // RNE; inputs finite
  return (ushort)(u >> 16);
}

// async global->LDS, 16B per lane; LDS dest = wave-uniform base + lane*16
static __device__ __forceinline__ void gl2lds16(const ushort* g, ushort* l) {
  __builtin_amdgcn_global_load_lds(
      (const __attribute__((address_space(1))) unsigned int*)g,
      (__attribute__((address_space(3))) unsigned int*)l, 16, 0, 0);
}

// ---------------- fp32 -> bf16 conversion (vectorized x4) ----------------
__global__ void cvt_bf16_kernel(const float* __restrict__ src,
                                ushort* __restrict__ dst, int n4) {
  int i = blockIdx.x * 256 + threadIdx.x;
  if (i >= n4) return;
  float4 v = ((const float4*)src)[i];
  ushort4 o;
  o.x = f2bf(v.x); o.y = f2bf(v.y); o.z = f2bf(v.z); o.w = f2bf(v.w);
  ((ushort4*)dst)[i] = o;
}

// ------- C[M][N] = A[M][K] * B[N][K]^T, 128x128 tile, global_load_lds -----
__global__ __launch_bounds__(256) void gemm128_bt_kernel(
    const ushort* __restrict__ A, const ushort* __restrict__ B,
    float* __restrict__ C, int M, int N, int K) {
  __shared__ __align__(16) ushort As[128 * BK];  // row-major [128][32], no pad
  __shared__ __align__(16) ushort Bs[128 * BK];

  const int tid  = threadIdx.x;
  const int wave = tid >> 6;
  const int lane = tid & 63;
  const int r16  = lane & 15;
  const int quad = lane >> 4;

  const int m_base = blockIdx.y * 128;
  const int n_base = blockIdx.x * 128;
  const int wm = (wave & 1) * 64;
  const int wn = (wave >> 1) * 64;

  const int srow = wave * 32 + (lane >> 2);
  const int scol = (lane & 3) * 8;
  const ushort* ag0 = A + (size_t)(m_base + srow) * K + scol;
  const ushort* ag1 = ag0 + (size_t)16 * K;
  const ushort* bg0 = B + (size_t)(n_base + srow) * K + scol;
  const ushort* bg1 = bg0 + (size_t)16 * K;
  ushort* as0 = As + (wave * 32) * BK;
  ushort* as1 = As + (wave * 32 + 16) * BK;
  ushort* bs0 = Bs + (wave * 32) * BK;
  ushort* bs1 = Bs + (wave * 32 + 16) * BK;

  floatx4 acc[4][4];
#pragma unroll
  for (int i = 0; i < 4; ++i)
#pragma unroll
    for (int j = 0; j < 4; ++j) acc[i][j] = floatx4{0.f, 0.f, 0.f, 0.f};

  for (int kk = 0; kk < K; kk += BK) {
    __syncthreads();
    gl2lds16(ag0 + kk, as0);
    gl2lds16(ag1 + kk, as1);
    gl2lds16(bg0 + kk, bs0);
    gl2lds16(bg1 + kk, bs1);
    __syncthreads();

    short8 af[4], bf[4];
#pragma unroll
    for (int i = 0; i < 4; ++i)
      af[i] = *(const short8*)&As[(wm + i * 16 + r16) * BK + quad * 8];
#pragma unroll
    for (int j = 0; j < 4; ++j)
      bf[j] = *(const short8*)&Bs[(wn + j * 16 + r16) * BK + quad * 8];
#pragma unroll
    for (int i = 0; i < 4; ++i)
#pragma unroll
      for (int j = 0; j < 4; ++j)
        acc[i][j] = __builtin_amdgcn_mfma_f32_16x16x32_bf16(af[i], bf[j], acc[i][j], 0, 0, 0);
  }

#pragma unroll
  for (int i = 0; i < 4; ++i)
#pragma unroll
    for (int j = 0; j < 4; ++j) {
      const int cm = m_base + wm + i * 16 + quad * 4;
      const int cn = n_base + wn + j * 16 + r16;
#pragma unroll
      for (int r = 0; r < 4; ++r)
        C[(size_t)(cm + r) * N + cn] = acc[i][j][r];
    }
}

// ---------------- RoPE + transpose to bf16 [nh][S][64] --------------------
__global__ void rope_kernel(const float* __restrict__ lin,  // [S][ld] (+col off)
                            ushort* __restrict__ outp,      // [nh][S][64] bf16
                            const int* __restrict__ pos_ids,
                            int nh, int sh, int ld) {
  int idx = blockIdx.x * 256 + threadIdx.x;  // exact: S*nh*32 threads
  int d2 = idx & 31;
  int h  = (idx >> 5) & (nh - 1);
  int s  = idx >> (5 + sh);
  float pos  = (float)pos_ids[s];
  float invf = powf(10000.0f, -(2.0f * (float)d2) * (1.0f / 64.0f));
  float sn, cs;
  sincosf(pos * invf, &sn, &cs);
  float x1 = lin[(size_t)s * ld + h * 64 + d2];
  float x2 = lin[(size_t)s * ld + h * 64 + d2 + 32];
  outp[((size_t)h * S_LEN + s) * 64 + d2]      = f2bf(x1 * cs - x2 * sn);
  outp[((size_t)h * S_LEN + s) * 64 + d2 + 32] = f2bf(x2 * cs + x1 * sn);
}

// ---------------- V cols of fused out -> bf16 Vt [NKV][64][S] -------------
__global__ void transpose_v_kernel(const float* __restrict__ lin,  // +col off
                                   ushort* __restrict__ vt, int ld) {
  int idx = blockIdx.x * 256 + threadIdx.x;  // NKV*HD*(S/4) threads
  int s4 = idx & (S_LEN / 4 - 1);
  int d  = (idx >> 9) & 63;
  int h  = idx >> 15;
  const float* src = lin + (size_t)(s4 * 4) * ld + h * 64 + d;
  ushort4 o;
  o.x = f2bf(src[0 * ld]);
  o.y = f2bf(src[1 * ld]);
  o.z = f2bf(src[2 * ld]);
  o.w = f2bf(src[3 * ld]);
  ((ushort4*)vt)[idx] = o;  // vt[h][d][s4*4 .. +3]
}

// ---------------- causal GQA flash attention (MFMA bf16) ------------------
// Scores TRANSPOSED (S^T[key][q]); per-lane softmax state (q = lane&15);
// P goes through a small per-wave LDS buffer (aligned b64 writes, b128 reads,
// wave-internal so no barrier); PV uses the same 16x16x32 MFMA as the GEMMs.
#define LOG2E_SC 0.180336880f   // (1/sqrt(64)) * log2(e)

__global__ __launch_bounds__(256) void attn_kernel(
    const ushort* __restrict__ Q,   // [NH][S][64]  bf16 roped
    const ushort* __restrict__ K,   // [NKV][S][64] bf16 roped
    const ushort* __restrict__ Vt,  // [NKV][64][S] bf16
    ushort* __restrict__ O) {       // [S][NH*64]   bf16
  __shared__ __align__(16) ushort Ks[64][72];      // K tile  [k][d]
  __shared__ __align__(16) ushort Vs[64][72];      // Vt tile [d][k]
  __shared__ __align__(16) ushort Pw[4][16][72];   // per-wave P [q=r16][key]

  const int h    = blockIdx.x;
  const int kh   = h >> 2;                         // GROUPS = 4
  const int y    = blockIdx.y;
  const int qt   = (y & 1) ? (31 - (y >> 1)) : (y >> 1);  // load balance
  const int tid  = threadIdx.x;
  const int wave = tid >> 6;
  const int lane = tid & 63;
  const int r16  = lane & 15;
  const int quad = lane >> 4;

  // Q fragment: B-operand of scores mfma (n = q = r16)
  const ushort* qp = Q + ((size_t)h * S_LEN + qt * 64 + wave * 16 + r16) * 64 + quad * 8;
  const short8 qf0 = *(const short8*)(qp);
  const short8 qf1 = *(const short8*)(qp + 32);

  const int q_glob = qt * 64 + wave * 16 + r16;   // this lane's query row

  float m_run = -1e30f, l_run = 0.f;
  floatx4 oacc[4];                                 // O^T[d-tile][q=r16]
#pragma unroll
  for (int n = 0; n < 4; ++n) oacc[n] = floatx4{0.f, 0.f, 0.f, 0.f};

  for (int kt = 0; kt <= qt; ++kt) {
    __syncthreads();
    {
      const ushort* ksrc = K  + ((size_t)kh * S_LEN + kt * 64) * 64;
      const ushort* vsrc = Vt + ((size_t)kh * 64) * S_LEN + kt * 64;
#pragma unroll
      for (int i = tid; i < 512; i += 256) {
        int r = i >> 3, c = (i & 7) * 8;
        *(short8*)&Ks[r][c] = *(const short8*)(ksrc + (size_t)r * 64 + c);
        *(short8*)&Vs[r][c] = *(const short8*)(vsrc + (size_t)r * S_LEN + c);
      }
    }
    __syncthreads();

    // ---- scores transposed: S^T[key][q], 4 key-chunks of 16 ----
    floatx4 sacc[4];
#pragma unroll
    for (int t = 0; t < 4; ++t) {
      short8 kf0 = *(const short8*)&Ks[t * 16 + r16][quad * 8];
      short8 kf1 = *(const short8*)&Ks[t * 16 + r16][32 + quad * 8];
      floatx4 z = {0.f, 0.f, 0.f, 0.f};
      z = __builtin_amdgcn_mfma_f32_16x16x32_bf16(kf0, qf0, z, 0, 0, 0);
      sacc[t] = __builtin_amdgcn_mfma_f32_16x16x32_bf16(kf1, qf1, z, 0, 0, 0);
    }

    // scale into base-2 domain + causal mask (lane's key = kt*64+t*16+quad*4+r)
    const bool diag = (kt == qt);
#pragma unroll
    for (int t = 0; t < 4; ++t)
#pragma unroll
      for (int r = 0; r < 4; ++r) {
        float sc = sacc[t][r] * LOG2E_SC;
        if (diag && (kt * 64 + t * 16 + quad * 4 + r) > q_glob) sc = -1e30f;
        sacc[t][r] = sc;
      }

    // ---- per-lane online softmax (state per q = r16; reduce over quads) ----
    float mx = -1e30f;
#pragma unroll
    for (int t = 0; t < 4; ++t)
#pragma unroll
      for (int r = 0; r < 4; ++r) mx = fmaxf(mx, sacc[t][r]);
    mx = fmaxf(mx, __shfl_xor(mx, 16));
    mx = fmaxf(mx, __shfl_xor(mx, 32));
    float mnew  = fmaxf(m_run, mx);
    float alpha = __builtin_amdgcn_exp2f(m_run - mnew);
    m_run = mnew;

    float ps = 0.f;
#pragma unroll
    for (int t = 0; t < 4; ++t) {
      float p0 = __builtin_amdgcn_exp2f(sacc[t][0] - mnew);
      float p1 = __builtin_amdgcn_exp2f(sacc[t][1] - mnew);
      float p2 = __builtin_amdgcn_exp2f(sacc[t][2] - mnew);
      float p3 = __builtin_amdgcn_exp2f(sacc[t][3] - mnew);
      ps += (p0 + p1) + (p2 + p3);
      // aligned b64 write: P[q=r16][key = t*16 + quad*4 + 0..3]
      *(short4x*)&Pw[wave][r16][t * 16 + quad * 4] =
          short4x{(short)f2bf(p0), (short)f2bf(p1),
                  (short)f2bf(p2), (short)f2bf(p3)};
    }
    ps += __shfl_xor(ps, 16);
    ps += __shfl_xor(ps, 32);
    l_run = l_run * alpha + ps;

    // ---- PV (K=32 MFMA): O^T[d][q] += V^T * P; wave-internal LDS dep ----
    short8 pf0 = *(const short8*)&Pw[wave][r16][quad * 8];
    short8 pf1 = *(const short8*)&Pw[wave][r16][32 + quad * 8];
#pragma unroll
    for (int n = 0; n < 4; ++n) {
      oacc[n][0] *= alpha; oacc[n][1] *= alpha;
      oacc[n][2] *= alpha; oacc[n][3] *= alpha;
      short8 vf0 = *(const short8*)&Vs[n * 16 + r16][quad * 8];
      short8 vf1 = *(const short8*)&Vs[n * 16 + r16][32 + quad * 8];
      oacc[n] = __builtin_amdgcn_mfma_f32_16x16x32_bf16(vf0, pf0, oacc[n], 0, 0, 0);
      oacc[n] = __builtin_amdgcn_mfma_f32_16x16x32_bf16(vf1, pf1, oacc[n], 0, 0, 0);
    }
  }

  // epilogue: lane holds O^T[d = n*16 + quad*4 + r][q = r16]
  const float inv_l = 1.f / l_run;
#pragma unroll
  for (int n = 0; n < 4; ++n) {
    ushort4 o4;
    o4.x = f2bf(oacc[n][0] * inv_l);
    o4.y = f2bf(oacc[n][1] * inv_l);
    o4.z = f2bf(oacc[n][2] * inv_l);
    o4.w = f2bf(oacc[n][3] * inv_l);
    *(ushort4*)&O[(size_t)q_glob * (NH * HD) + h * 64 + n * 16 + quad * 4] = o4;
  }
}

// --------------------------------------------------------------------------
extern "C" void kernel_launch(void* const* d_in, const int* in_sizes, int n_in,
                              void* d_out, int out_size, void* d_ws, size_t ws_size,
                              hipStream_t stream) {
  const float* hidden = (const float*)d_in[0];
  const int*   pos    = (const int*)d_in[2];
  const float* Wq     = (const float*)d_in[3];
  const float* Wk     = (const float*)d_in[4];
  const float* Wv     = (const float*)d_in[5];
  const float* Wo     = (const float*)d_in[6];
  float* out = (float*)d_out;

  const int NQKV = HID + 2 * NKV * HD;  // 3072 fused output cols

  char* w = (char*)d_ws;
  auto carve = [&](size_t bytes) { char* p = w; w += bytes; return p; };
  ushort* hb    = (ushort*)carve((size_t)S_LEN * HID * 2);
  ushort* wqkvb = (ushort*)carve((size_t)NQKV * HID * 2);    // concat(Wq,Wk,Wv)
  ushort* wob   = (ushort*)carve((size_t)HID * HID * 2);
  float*  qkvl  = (float*)carve((size_t)S_LEN * NQKV * 4);   // fused [S][3072]
  ushort* qr    = (ushort*)carve((size_t)NH * S_LEN * HD * 2);
  ushort* kr    = (ushort*)carve((size_t)NKV * S_LEN * HD * 2);
  ushort* vtb   = (ushort*)carve((size_t)NKV * HD * S_LEN * 2);
  ushort* ob    = (ushort*)carve((size_t)S_LEN * HID * 2);

  // 1) bf16 conversions (weights concatenated row-wise: Wq | Wk | Wv)
  cvt_bf16_kernel<<<(S_LEN * HID / 4) / 256, 256, 0, stream>>>(hidden, hb, S_LEN * HID / 4);
  cvt_bf16_kernel<<<(HID * HID / 4) / 256, 256, 0, stream>>>(Wq, wqkvb, HID * HID / 4);
  cvt_bf16_kernel<<<(NKV * HD * HID / 4) / 256, 256, 0, stream>>>(
      Wk, wqkvb + (size_t)HID * HID, NKV * HD * HID / 4);
  cvt_bf16_kernel<<<(NKV * HD * HID / 4) / 256, 256, 0, stream>>>(
      Wv, wqkvb + (size_t)(HID + NKV * HD) * HID, NKV * HD * HID / 4);
  cvt_bf16_kernel<<<(HID * HID / 4) / 256, 256, 0, stream>>>(Wo, wob, HID * HID / 4);

  // 2) fused QKV projection: [2048][2048] x [3072][2048]^T -> [2048][3072]
  dim3 gqkv(NQKV / 128, S_LEN / 128);
  gemm128_bt_kernel<<<gqkv, 256, 0, stream>>>(hb, wqkvb, qkvl, S_LEN, NQKV, HID);

  // 3) RoPE (-> bf16 head-major) + V transpose (-> bf16 [h][d][s])
  rope_kernel<<<(S_LEN * NH * 32) / 256, 256, 0, stream>>>(qkvl, qr, pos, NH, 5, NQKV);
  rope_kernel<<<(S_LEN * NKV * 32) / 256, 256, 0, stream>>>(qkvl + HID, kr, pos, NKV, 3, NQKV);
  transpose_v_kernel<<<(NKV * HD * S_LEN / 4) / 256, 256, 0, stream>>>(
      qkvl + HID + NKV * HD, vtb, NQKV);

  // 4) causal GQA attention (MFMA) -> bf16 [S][NH*HD]
  dim3 ga(NH, S_LEN / 64);
  attn_kernel<<<ga, 256, 0, stream>>>(qr, kr, vtb, ob);

  // 5) output projection -> fp32 d_out
  dim3 go(HID / 128, S_LEN / 128);
  gemm128_bt_kernel<<<go, 256, 0, stream>>>(ob, wob, out, S_LEN, HID, HID);
}

// Round 8
// 267.694 us; speedup vs baseline: 5.0497x; 1.1295x over previous
//
#include <hip/hip_runtime.h>
#include <math.h>

#define S_LEN 2048
#define HID   2048
#define NH    32
#define NKV   8
#define HD    64
#define BK    32

typedef short short4x __attribute__((ext_vector_type(4)));
typedef short short8  __attribute__((ext_vector_type(8)));
typedef float floatx4 __attribute__((ext_vector_type(4)));

static __device__ __forceinline__ ushort f2bf(float f) {
  unsigned u = __float_as_uint(f);
  u += 0x7fffu + ((u >> 16) & 1u);   // RNE; inputs finite
  return (ushort)(u >> 16);
}

// async global->LDS, 16B per lane; LDS dest = wave-uniform base + lane*16
static __device__ __forceinline__ void gl2lds16(const ushort* g, ushort* l) {
  __builtin_amdgcn_global_load_lds(
      (const __attribute__((address_space(1))) unsigned int*)g,
      (__attribute__((address_space(3))) unsigned int*)l, 16, 0, 0);
}

// ---------------- all fp32 -> bf16 conversions, one launch ----------------
// region boundaries are multiples of 256 quads -> no intra-block divergence
#define QH  1048576   // hidden  quads (S*HID/4)
#define QW  1048576   // Wq      quads
#define QKq  262144   // Wk      quads
#define QVq  262144   // Wv      quads
#define QO  1048576   // Wo      quads
__global__ void cvt_all_kernel(const float* __restrict__ h,
                               const float* __restrict__ wq,
                               const float* __restrict__ wk,
                               const float* __restrict__ wv,
                               const float* __restrict__ wo,
                               ushort* __restrict__ hb,
                               ushort* __restrict__ wqkvb,
                               ushort* __restrict__ wob) {
  int idx = blockIdx.x * 256 + threadIdx.x;
  const float* src; ushort* dst; int so, dqo;
  if (idx < QH)                    { src = h;  dst = hb;    so = idx;                   dqo = so; }
  else if (idx < QH + QW)          { src = wq; dst = wqkvb; so = idx - QH;              dqo = so; }
  else if (idx < QH + QW + QKq)    { src = wk; dst = wqkvb; so = idx - QH - QW;         dqo = so + QW; }
  else if (idx < QH + QW + QKq + QVq) { src = wv; dst = wqkvb; so = idx - QH - QW - QKq; dqo = so + QW + QKq; }
  else                             { src = wo; dst = wob;   so = idx - QH - QW - QKq - QVq; dqo = so; }
  float4 v = ((const float4*)src)[so];
  ushort4 o;
  o.x = f2bf(v.x); o.y = f2bf(v.y); o.z = f2bf(v.z); o.w = f2bf(v.w);
  ((ushort4*)dst)[dqo] = o;
}

// ------- C[M][N] = A[M][K] * B[N][K]^T, 128x128 tile, global_load_lds -----
__global__ __launch_bounds__(256) void gemm128_bt_kernel(
    const ushort* __restrict__ A, const ushort* __restrict__ B,
    float* __restrict__ C, int M, int N, int K) {
  __shared__ __align__(16) ushort As[128 * BK];  // row-major [128][32], no pad
  __shared__ __align__(16) ushort Bs[128 * BK];

  const int tid  = threadIdx.x;
  const int wave = tid >> 6;
  const int lane = tid & 63;
  const int r16  = lane & 15;
  const int quad = lane >> 4;

  const int m_base = blockIdx.y * 128;
  const int n_base = blockIdx.x * 128;
  const int wm = (wave & 1) * 64;
  const int wn = (wave >> 1) * 64;

  const int srow = wave * 32 + (lane >> 2);
  const int scol = (lane & 3) * 8;
  const ushort* ag0 = A + (size_t)(m_base + srow) * K + scol;
  const ushort* ag1 = ag0 + (size_t)16 * K;
  const ushort* bg0 = B + (size_t)(n_base + srow) * K + scol;
  const ushort* bg1 = bg0 + (size_t)16 * K;
  ushort* as0 = As + (wave * 32) * BK;
  ushort* as1 = As + (wave * 32 + 16) * BK;
  ushort* bs0 = Bs + (wave * 32) * BK;
  ushort* bs1 = Bs + (wave * 32 + 16) * BK;

  floatx4 acc[4][4];
#pragma unroll
  for (int i = 0; i < 4; ++i)
#pragma unroll
    for (int j = 0; j < 4; ++j) acc[i][j] = floatx4{0.f, 0.f, 0.f, 0.f};

  for (int kk = 0; kk < K; kk += BK) {
    __syncthreads();
    gl2lds16(ag0 + kk, as0);
    gl2lds16(ag1 + kk, as1);
    gl2lds16(bg0 + kk, bs0);
    gl2lds16(bg1 + kk, bs1);
    __syncthreads();

    short8 af[4], bf[4];
#pragma unroll
    for (int i = 0; i < 4; ++i)
      af[i] = *(const short8*)&As[(wm + i * 16 + r16) * BK + quad * 8];
#pragma unroll
    for (int j = 0; j < 4; ++j)
      bf[j] = *(const short8*)&Bs[(wn + j * 16 + r16) * BK + quad * 8];
#pragma unroll
    for (int i = 0; i < 4; ++i)
#pragma unroll
      for (int j = 0; j < 4; ++j)
        acc[i][j] = __builtin_amdgcn_mfma_f32_16x16x32_bf16(af[i], bf[j], acc[i][j], 0, 0, 0);
  }

#pragma unroll
  for (int i = 0; i < 4; ++i)
#pragma unroll
    for (int j = 0; j < 4; ++j) {
      const int cm = m_base + wm + i * 16 + quad * 4;
      const int cn = n_base + wn + j * 16 + r16;
#pragma unroll
      for (int r = 0; r < 4; ++r)
        C[(size_t)(cm + r) * N + cn] = acc[i][j][r];
    }
}

// ---- fused QKV GEMM: same K-loop, epilogue does RoPE + bf16 + layout -----
// A = hb [S][HID], B = wqkvb [3072][HID].  Wave's 64-col quadrant = 1 head.
__global__ __launch_bounds__(256) void gemm_qkv_kernel(
    const ushort* __restrict__ A, const ushort* __restrict__ B,
    const int* __restrict__ pos,
    ushort* __restrict__ qr,    // [NH][S][64]  bf16 roped
    ushort* __restrict__ kr,    // [NKV][S][64] bf16 roped
    ushort* __restrict__ vtb) { // [NKV][64][S] bf16
  __shared__ __align__(16) ushort As[128 * BK];
  __shared__ __align__(16) ushort Bs[128 * BK];

  const int K = HID;
  const int tid  = threadIdx.x;
  const int wave = tid >> 6;
  const int lane = tid & 63;
  const int r16  = lane & 15;
  const int quad = lane >> 4;

  const int m_base = blockIdx.y * 128;
  const int n_base = blockIdx.x * 128;
  const int wm = (wave & 1) * 64;
  const int wn = (wave >> 1) * 64;

  const int srow = wave * 32 + (lane >> 2);
  const int scol = (lane & 3) * 8;
  const ushort* ag0 = A + (size_t)(m_base + srow) * K + scol;
  const ushort* ag1 = ag0 + (size_t)16 * K;
  const ushort* bg0 = B + (size_t)(n_base + srow) * K + scol;
  const ushort* bg1 = bg0 + (size_t)16 * K;
  ushort* as0 = As + (wave * 32) * BK;
  ushort* as1 = As + (wave * 32 + 16) * BK;
  ushort* bs0 = Bs + (wave * 32) * BK;
  ushort* bs1 = Bs + (wave * 32 + 16) * BK;

  floatx4 acc[4][4];
#pragma unroll
  for (int i = 0; i < 4; ++i)
#pragma unroll
    for (int j = 0; j < 4; ++j) acc[i][j] = floatx4{0.f, 0.f, 0.f, 0.f};

  for (int kk = 0; kk < K; kk += BK) {
    __syncthreads();
    gl2lds16(ag0 + kk, as0);
    gl2lds16(ag1 + kk, as1);
    gl2lds16(bg0 + kk, bs0);
    gl2lds16(bg1 + kk, bs1);
    __syncthreads();

    short8 af[4], bf[4];
#pragma unroll
    for (int i = 0; i < 4; ++i)
      af[i] = *(const short8*)&As[(wm + i * 16 + r16) * BK + quad * 8];
#pragma unroll
    for (int j = 0; j < 4; ++j)
      bf[j] = *(const short8*)&Bs[(wn + j * 16 + r16) * BK + quad * 8];
#pragma unroll
    for (int i = 0; i < 4; ++i)
#pragma unroll
      for (int j = 0; j < 4; ++j)
        acc[i][j] = __builtin_amdgcn_mfma_f32_16x16x32_bf16(af[i], bf[j], acc[i][j], 0, 0, 0);
  }

  // ---- epilogue: wave-uniform head = cols [n0w, n0w+64) ----
  const int n0w = n_base + wn;
  if (n0w < HID + NKV * HD) {
    // Q or K head: RoPE.  lane cols: j*16+r16 -> pairs (j0,j2)=(d2A,d2A+32),
    // (j1,j3)=(d2B,d2B+32) with d2A=r16, d2B=16+r16.
    ushort* dst;
    if (n0w < HID) dst = qr + (size_t)(n0w >> 6) * S_LEN * 64;
    else           dst = kr + (size_t)((n0w - HID) >> 6) * S_LEN * 64;
    const float invfA = powf(10000.0f, -(float)r16 * (1.0f / 32.0f));
    const float invfB = powf(10000.0f, -(float)(16 + r16) * (1.0f / 32.0f));
#pragma unroll
    for (int i = 0; i < 4; ++i) {
#pragma unroll
      for (int r = 0; r < 4; ++r) {
        const int s = m_base + wm + i * 16 + quad * 4 + r;
        const float p = (float)pos[s];
        float snA, csA, snB, csB;
        sincosf(p * invfA, &snA, &csA);
        sincosf(p * invfB, &snB, &csB);
        ushort* row = dst + (size_t)s * 64;
        row[r16]      = f2bf(acc[i][0][r] * csA - acc[i][2][r] * snA);
        row[16 + r16] = f2bf(acc[i][1][r] * csB - acc[i][3][r] * snB);
        row[32 + r16] = f2bf(acc[i][2][r] * csA + acc[i][0][r] * snA);
        row[48 + r16] = f2bf(acc[i][3][r] * csB + acc[i][1][r] * snB);
      }
    }
  } else {
    // V head: transposed store vtb[h][d][s]; 4 consecutive s pack to ushort4
    const int hh = (n0w - HID - NKV * HD) >> 6;
#pragma unroll
    for (int i = 0; i < 4; ++i) {
      const int s0 = m_base + wm + i * 16 + quad * 4;
#pragma unroll
      for (int j = 0; j < 4; ++j) {
        const int d = j * 16 + r16;
        ushort4 o4;
        o4.x = f2bf(acc[i][j][0]);
        o4.y = f2bf(acc[i][j][1]);
        o4.z = f2bf(acc[i][j][2]);
        o4.w = f2bf(acc[i][j][3]);
        *(ushort4*)&vtb[((size_t)hh * 64 + d) * S_LEN + s0] = o4;
      }
    }
  }
}

// ---------------- causal GQA flash attention (MFMA bf16) ------------------
#define LOG2E_SC 0.180336880f   // (1/sqrt(64)) * log2(e)

__global__ __launch_bounds__(256) void attn_kernel(
    const ushort* __restrict__ Q,   // [NH][S][64]  bf16 roped
    const ushort* __restrict__ K,   // [NKV][S][64] bf16 roped
    const ushort* __restrict__ Vt,  // [NKV][64][S] bf16
    ushort* __restrict__ O) {       // [S][NH*64]   bf16
  __shared__ __align__(16) ushort Ks[64][72];      // K tile  [k][d]
  __shared__ __align__(16) ushort Vs[64][72];      // Vt tile [d][k]
  __shared__ __align__(16) ushort Pw[4][16][72];   // per-wave P [q=r16][key]

  const int h    = blockIdx.x;
  const int kh   = h >> 2;                         // GROUPS = 4
  const int y    = blockIdx.y;
  const int qt   = (y & 1) ? (31 - (y >> 1)) : (y >> 1);  // load balance
  const int tid  = threadIdx.x;
  const int wave = tid >> 6;
  const int lane = tid & 63;
  const int r16  = lane & 15;
  const int quad = lane >> 4;

  const ushort* qp = Q + ((size_t)h * S_LEN + qt * 64 + wave * 16 + r16) * 64 + quad * 8;
  const short8 qf0 = *(const short8*)(qp);
  const short8 qf1 = *(const short8*)(qp + 32);

  const int q_glob = qt * 64 + wave * 16 + r16;   // this lane's query row

  float m_run = -1e30f, l_run = 0.f;
  floatx4 oacc[4];                                 // O^T[d-tile][q=r16]
#pragma unroll
  for (int n = 0; n < 4; ++n) oacc[n] = floatx4{0.f, 0.f, 0.f, 0.f};

  for (int kt = 0; kt <= qt; ++kt) {
    __syncthreads();
    {
      const ushort* ksrc = K  + ((size_t)kh * S_LEN + kt * 64) * 64;
      const ushort* vsrc = Vt + ((size_t)kh * 64) * S_LEN + kt * 64;
#pragma unroll
      for (int i = tid; i < 512; i += 256) {
        int r = i >> 3, c = (i & 7) * 8;
        *(short8*)&Ks[r][c] = *(const short8*)(ksrc + (size_t)r * 64 + c);
        *(short8*)&Vs[r][c] = *(const short8*)(vsrc + (size_t)r * S_LEN + c);
      }
    }
    __syncthreads();

    // ---- scores transposed: S^T[key][q], 4 key-chunks of 16 ----
    floatx4 sacc[4];
#pragma unroll
    for (int t = 0; t < 4; ++t) {
      short8 kf0 = *(const short8*)&Ks[t * 16 + r16][quad * 8];
      short8 kf1 = *(const short8*)&Ks[t * 16 + r16][32 + quad * 8];
      floatx4 z = {0.f, 0.f, 0.f, 0.f};
      z = __builtin_amdgcn_mfma_f32_16x16x32_bf16(kf0, qf0, z, 0, 0, 0);
      sacc[t] = __builtin_amdgcn_mfma_f32_16x16x32_bf16(kf1, qf1, z, 0, 0, 0);
    }

    const bool diag = (kt == qt);
#pragma unroll
    for (int t = 0; t < 4; ++t)
#pragma unroll
      for (int r = 0; r < 4; ++r) {
        float sc = sacc[t][r] * LOG2E_SC;
        if (diag && (kt * 64 + t * 16 + quad * 4 + r) > q_glob) sc = -1e30f;
        sacc[t][r] = sc;
      }

    // ---- per-lane online softmax (state per q = r16; reduce over quads) ----
    float mx = -1e30f;
#pragma unroll
    for (int t = 0; t < 4; ++t)
#pragma unroll
      for (int r = 0; r < 4; ++r) mx = fmaxf(mx, sacc[t][r]);
    mx = fmaxf(mx, __shfl_xor(mx, 16));
    mx = fmaxf(mx, __shfl_xor(mx, 32));
    float mnew  = fmaxf(m_run, mx);
    float alpha = __builtin_amdgcn_exp2f(m_run - mnew);
    m_run = mnew;

    float ps = 0.f;
#pragma unroll
    for (int t = 0; t < 4; ++t) {
      float p0 = __builtin_amdgcn_exp2f(sacc[t][0] - mnew);
      float p1 = __builtin_amdgcn_exp2f(sacc[t][1] - mnew);
      float p2 = __builtin_amdgcn_exp2f(sacc[t][2] - mnew);
      float p3 = __builtin_amdgcn_exp2f(sacc[t][3] - mnew);
      ps += (p0 + p1) + (p2 + p3);
      *(short4x*)&Pw[wave][r16][t * 16 + quad * 4] =
          short4x{(short)f2bf(p0), (short)f2bf(p1),
                  (short)f2bf(p2), (short)f2bf(p3)};
    }
    ps += __shfl_xor(ps, 16);
    ps += __shfl_xor(ps, 32);
    l_run = l_run * alpha + ps;

    // ---- PV (K=32 MFMA): O^T[d][q] += V^T * P; wave-internal LDS dep ----
    short8 pf0 = *(const short8*)&Pw[wave][r16][quad * 8];
    short8 pf1 = *(const short8*)&Pw[wave][r16][32 + quad * 8];
#pragma unroll
    for (int n = 0; n < 4; ++n) {
      oacc[n][0] *= alpha; oacc[n][1] *= alpha;
      oacc[n][2] *= alpha; oacc[n][3] *= alpha;
      short8 vf0 = *(const short8*)&Vs[n * 16 + r16][quad * 8];
      short8 vf1 = *(const short8*)&Vs[n * 16 + r16][32 + quad * 8];
      oacc[n] = __builtin_amdgcn_mfma_f32_16x16x32_bf16(vf0, pf0, oacc[n], 0, 0, 0);
      oacc[n] = __builtin_amdgcn_mfma_f32_16x16x32_bf16(vf1, pf1, oacc[n], 0, 0, 0);
    }
  }

  // epilogue: lane holds O^T[d = n*16 + quad*4 + r][q = r16]
  const float inv_l = 1.f / l_run;
#pragma unroll
  for (int n = 0; n < 4; ++n) {
    ushort4 o4;
    o4.x = f2bf(oacc[n][0] * inv_l);
    o4.y = f2bf(oacc[n][1] * inv_l);
    o4.z = f2bf(oacc[n][2] * inv_l);
    o4.w = f2bf(oacc[n][3] * inv_l);
    *(ushort4*)&O[(size_t)q_glob * (NH * HD) + h * 64 + n * 16 + quad * 4] = o4;
  }
}

// --------------------------------------------------------------------------
extern "C" void kernel_launch(void* const* d_in, const int* in_sizes, int n_in,
                              void* d_out, int out_size, void* d_ws, size_t ws_size,
                              hipStream_t stream) {
  const float* hidden = (const float*)d_in[0];
  const int*   pos    = (const int*)d_in[2];
  const float* Wq     = (const float*)d_in[3];
  const float* Wk     = (const float*)d_in[4];
  const float* Wv     = (const float*)d_in[5];
  const float* Wo     = (const float*)d_in[6];
  float* out = (float*)d_out;

  const int NQKV = HID + 2 * NKV * HD;  // 3072 fused output cols

  char* w = (char*)d_ws;
  auto carve = [&](size_t bytes) { char* p = w; w += bytes; return p; };
  ushort* hb    = (ushort*)carve((size_t)S_LEN * HID * 2);
  ushort* wqkvb = (ushort*)carve((size_t)NQKV * HID * 2);    // concat(Wq,Wk,Wv)
  ushort* wob   = (ushort*)carve((size_t)HID * HID * 2);
  ushort* qr    = (ushort*)carve((size_t)NH * S_LEN * HD * 2);
  ushort* kr    = (ushort*)carve((size_t)NKV * S_LEN * HD * 2);
  ushort* vtb   = (ushort*)carve((size_t)NKV * HD * S_LEN * 2);
  ushort* ob    = (ushort*)carve((size_t)S_LEN * HID * 2);

  // 1) all bf16 conversions, one launch
  cvt_all_kernel<<<(QH + QW + QKq + QVq + QO) / 256, 256, 0, stream>>>(
      hidden, Wq, Wk, Wv, Wo, hb, wqkvb, wob);

  // 2) fused QKV projection + RoPE + head-major/V-transpose epilogue
  dim3 gqkv(NQKV / 128, S_LEN / 128);
  gemm_qkv_kernel<<<gqkv, 256, 0, stream>>>(hb, wqkvb, pos, qr, kr, vtb);

  // 3) causal GQA attention (MFMA) -> bf16 [S][NH*HD]
  dim3 ga(NH, S_LEN / 64);
  attn_kernel<<<ga, 256, 0, stream>>>(qr, kr, vtb, ob);

  // 4) output projection -> fp32 d_out
  dim3 go(HID / 128, S_LEN / 128);
  gemm128_bt_kernel<<<go, 256, 0, stream>>>(ob, wob, out, S_LEN, HID, HID);
}